// Round 14
// baseline (14369.112 us; speedup 1.0000x reference)
//
#include <hip/hip_runtime.h>
#include <hip/hip_bf16.h>

#define T_STEPS 4096
#define BATCH 8
#define DIN 512
#define NH 512
#define G4 2048
#define NWV 32
#define JPW 16

typedef __attribute__((ext_vector_type(8))) short bf16x8;
typedef __attribute__((ext_vector_type(4))) float f32x4;
typedef __attribute__((ext_vector_type(4))) int i32x4;

__device__ __forceinline__ unsigned short f2b(float f) {
  __hip_bfloat16 h = __float2bfloat16(f);
  return __builtin_bit_cast(unsigned short, h);
}
__device__ __forceinline__ float b2f(unsigned short u) {
  unsigned int x = ((unsigned int)u) << 16;
  return __builtin_bit_cast(float, x);
}
__device__ __forceinline__ float sigf(float x) { return 1.f / (1.f + __expf(-x)); }
__device__ __forceinline__ float tanh_fast(float x) { return 1.f - 2.f / (1.f + __expf(2.f * x)); }

// ---------------- init: tags=0; hbuf parity0 = bf16(h0), parity1 = 0
__global__ __launch_bounds__(512) void init_ws(const float* __restrict__ h0,
                                               unsigned int* __restrict__ tags,
                                               unsigned short* __restrict__ hbuf) {
  int tid = threadIdx.x;
  if (tid < NWV) tags[tid] = 0u;
  for (int i = tid; i < 4096; i += 512) {   // [8 b][512 j] per parity
    int b = i >> 9, j = i & 511;
    hbuf[i] = f2b(h0[b * NH + j]);
    hbuf[4096 + i] = 0;
  }
}

// ---------------- XI = x @ Wi + (bi + bh), swizzled to [t][wv][lane(32)][g*4+q] u16
#define BM 64
#define BN 64
#define BK 16
__global__ __launch_bounds__(256) void xi_gemm(const float* __restrict__ x,
                                               const float* __restrict__ Wi,
                                               const float* __restrict__ bi,
                                               const float* __restrict__ bh,
                                               unsigned short* __restrict__ xi) {
  __shared__ float As[BK][BM + 4];
  __shared__ float Bs[BK][BN + 4];
  const int tid = threadIdx.x;
  const int m0 = blockIdx.x * BM;
  const int n0 = blockIdx.y * BN;
  const int tx = tid & 15, ty = tid >> 4;
  const int arow = tid & 63, ak = (tid >> 6) << 2;
  const int bk = tid >> 4, bn = (tid & 15) << 2;
  float acc[4][4] = {};
  for (int k0 = 0; k0 < DIN; k0 += BK) {
    float4 av = *(const float4*)(x + (size_t)(m0 + arow) * DIN + k0 + ak);
    float4 bv = *(const float4*)(Wi + (size_t)(k0 + bk) * G4 + n0 + bn);
    __syncthreads();
    As[ak + 0][arow] = av.x;
    As[ak + 1][arow] = av.y;
    As[ak + 2][arow] = av.z;
    As[ak + 3][arow] = av.w;
    *(float4*)&Bs[bk][bn] = bv;
    __syncthreads();
#pragma unroll
    for (int kk = 0; kk < BK; ++kk) {
      float am[4], bw[4];
      *(float4*)am = *(const float4*)&As[kk][ty << 2];
      *(float4*)bw = *(const float4*)&Bs[kk][tx << 2];
#pragma unroll
      for (int i = 0; i < 4; ++i)
#pragma unroll
        for (int j = 0; j < 4; ++j) acc[i][j] = fmaf(am[i], bw[j], acc[i][j]);
    }
  }
  const int m_base = m0 + (ty << 2);
  const int n_base = n0 + (tx << 2);
  const int tt = m_base >> 3;
  const int rg = (m_base & 7) >> 2;
  const int gate = n_base >> 9;
  const int wv = (n_base & 511) >> 4;
  const int col0 = n_base & 15;
#pragma unroll
  for (int j = 0; j < 4; ++j) {
    int n = n_base + j;
    float bs = bi[n] + bh[n];
    unsigned long long pk = 0;
#pragma unroll
    for (int i = 0; i < 4; ++i)
      pk |= (unsigned long long)f2b(acc[i][j] + bs) << (16 * i);
    int lane = rg * 16 + col0 + j;
    size_t u16idx = (((size_t)tt * NWV + wv) * 32 + lane) * 16 + gate * 4;
    *(unsigned long long*)(xi + u16idx) = pk;
  }
}

// ---------------- persistent recurrence: 32 blocks x 64 threads (1 wave each).
// R13 protocol with schedule fixes:
//  - no post-poll vmcnt(0): leftover poll load retires inside burst flight
//    (registers pinned via dummy asm use until vmcnt(14))
//  - burst issues immediately after poll; XI prefetch rides in burst shadow
//    (staged waits vmcnt(14/10/6/2) account for leftover + XI)
//  - progressive per-q publish stores inside gate computation
__global__ __launch_bounds__(64, 1) void lstm_rec(const float* __restrict__ Wh,
                                                  const float* __restrict__ h0c0,
                                                  const unsigned short* __restrict__ xi,
                                                  float* __restrict__ out,
                                                  unsigned int* tags,
                                                  unsigned short* hbuf) {
  const int wv = blockIdx.x;
  const int j0 = wv * JPW;
  const int lane = threadIdx.x;
  const int col = lane & 15;      // C col / loader batch-row
  const int rg = lane >> 4;       // C row-group / A k-subblock

  __shared__ bf16x8 bwS[4][16][64];   // 64 KiB frag-layout Wh slice

  // ---- prologue: Wh slice -> LDS in frag layout
  {
    const int gp = lane >> 4, cp = lane & 15;
    const float* wsrc = Wh + (size_t)gp * NH + j0 + cp;
#pragma unroll 4
    for (int k = 0; k < 512; ++k) {
      float wval = wsrc[(size_t)k * G4];
      const int ks = k >> 5, kq = (k >> 3) & 3, e = k & 7;
      ((unsigned short*)&bwS[gp][ks][kq * 16 + cp])[e] = f2b(wval);
    }
  }
  __syncthreads();

  bf16x8 bwR0[16], bwR1[16];
#pragma unroll
  for (int ks = 0; ks < 16; ++ks) {
    bwR0[ks] = bwS[0][ks][lane];
    bwR1[ks] = bwS[1][ks][lane];
  }

  f32x4 cell = {0.f, 0.f, 0.f, 0.f};
  if (lane < 32) {
#pragma unroll
    for (int q = 0; q < 4; ++q)
      cell[q] = h0c0[(size_t)(BATCH + rg * 4 + q) * NH + j0 + col];
  }

  // ---- XI(0) preload
  i32x4 xiC0, xiC1, xiN0, xiN1;
  {
    const unsigned short* xp = xi + ((size_t)wv * 32 + (lane & 31)) * 16;
    asm volatile("global_load_dwordx4 %0, %1, off" : "=&v"(xiC0) : "v"(xp));
    asm volatile("global_load_dwordx4 %0, %1, off offset:16" : "=&v"(xiC1) : "v"(xp));
  }
  f32x4 hq = {0.f, 0.f, 0.f, 0.f};

  const unsigned int* tp = tags + (lane & 31);
  unsigned int* myTag = tags + wv;

  for (int t = 0; t < T_STEPS; ++t) {
    // ---- (1) pipelined 2-deep tag poll; exit WITHOUT retiring the leftover load
    unsigned int tvA, tvB;
    {
      asm volatile("global_load_dword %0, %1, off sc1" : "=&v"(tvA) : "v"(tp) : "memory");
      for (;;) {
        asm volatile("global_load_dword %0, %1, off sc1" : "=&v"(tvB) : "v"(tp) : "memory");
        asm volatile("s_waitcnt vmcnt(1)" ::: "memory");   // tvA ready
        __builtin_amdgcn_sched_barrier(0);
        if (__all((int)tvA >= t)) break;
        asm volatile("global_load_dword %0, %1, off sc1" : "=&v"(tvA) : "v"(tp) : "memory");
        asm volatile("s_waitcnt vmcnt(1)" ::: "memory");   // tvB ready
        __builtin_amdgcn_sched_barrier(0);
        if (__all((int)tvB >= t)) break;
      }
    }

    // ---- (2) h(t) burst issues IMMEDIATELY (<=1 leftover poll load outstanding)
    const unsigned short* mb = hbuf + ((t & 1) << 12);
    const unsigned short* ap = mb + (col & 7) * 512 + (rg << 3);
    i32x4 afr[16];
    asm volatile("global_load_dwordx4 %0, %1, off sc1" : "=v"(afr[0]) : "v"(ap));
    asm volatile("global_load_dwordx4 %0, %1, off offset:64 sc1" : "=v"(afr[1]) : "v"(ap));
    asm volatile("global_load_dwordx4 %0, %1, off offset:128 sc1" : "=v"(afr[2]) : "v"(ap));
    asm volatile("global_load_dwordx4 %0, %1, off offset:192 sc1" : "=v"(afr[3]) : "v"(ap));
    asm volatile("global_load_dwordx4 %0, %1, off offset:256 sc1" : "=v"(afr[4]) : "v"(ap));
    asm volatile("global_load_dwordx4 %0, %1, off offset:320 sc1" : "=v"(afr[5]) : "v"(ap));
    asm volatile("global_load_dwordx4 %0, %1, off offset:384 sc1" : "=v"(afr[6]) : "v"(ap));
    asm volatile("global_load_dwordx4 %0, %1, off offset:448 sc1" : "=v"(afr[7]) : "v"(ap));
    asm volatile("global_load_dwordx4 %0, %1, off offset:512 sc1" : "=v"(afr[8]) : "v"(ap));
    asm volatile("global_load_dwordx4 %0, %1, off offset:576 sc1" : "=v"(afr[9]) : "v"(ap));
    asm volatile("global_load_dwordx4 %0, %1, off offset:640 sc1" : "=v"(afr[10]) : "v"(ap));
    asm volatile("global_load_dwordx4 %0, %1, off offset:704 sc1" : "=v"(afr[11]) : "v"(ap));
    asm volatile("global_load_dwordx4 %0, %1, off offset:768 sc1" : "=v"(afr[12]) : "v"(ap));
    asm volatile("global_load_dwordx4 %0, %1, off offset:832 sc1" : "=v"(afr[13]) : "v"(ap));
    asm volatile("global_load_dwordx4 %0, %1, off offset:896 sc1" : "=v"(afr[14]) : "v"(ap));
    asm volatile("global_load_dwordx4 %0, %1, off offset:960 sc1" : "=v"(afr[15]) : "v"(ap));
    // ---- (3) XI(t+1) prefetch rides in the burst shadow (retired by drain)
    {
      const int tn = (t + 1 < T_STEPS) ? (t + 1) : t;
      const unsigned short* xp = xi + (((size_t)tn * NWV + wv) * 32 + (lane & 31)) * 16;
      asm volatile("global_load_dwordx4 %0, %1, off" : "=&v"(xiN0) : "v"(xp));
      asm volatile("global_load_dwordx4 %0, %1, off offset:16" : "=&v"(xiN1) : "v"(xp));
    }

    // ---- (4) acc seed from XI (VALU; overlaps burst flight)
    f32x4 acc[4][2];
    {
      unsigned int wrd[8] = {(unsigned int)xiC0[0], (unsigned int)xiC0[1],
                             (unsigned int)xiC0[2], (unsigned int)xiC0[3],
                             (unsigned int)xiC1[0], (unsigned int)xiC1[1],
                             (unsigned int)xiC1[2], (unsigned int)xiC1[3]};
      f32x4 z = {0.f, 0.f, 0.f, 0.f};
#pragma unroll
      for (int g = 0; g < 4; ++g) {
#pragma unroll
        for (int q = 0; q < 4; ++q) {
          const int idx = g * 4 + q;
          acc[g][0][q] = b2f((unsigned short)(wrd[idx >> 1] >> ((idx & 1) * 16)));
        }
        acc[g][1] = z;
      }
    }

    // ---- (5) staged consume (in-order vmcnt retirement; counts include the
    //      leftover poll load (oldest) and the 2 XI loads (newest))
#define MFMA4(ks)                                                                          \
    {                                                                                      \
      bf16x8 a = __builtin_bit_cast(bf16x8, afr[ks]);                                      \
      acc[0][(ks) & 1] = __builtin_amdgcn_mfma_f32_16x16x32_bf16(a, bwR0[ks], acc[0][(ks) & 1], 0, 0, 0); \
      acc[1][(ks) & 1] = __builtin_amdgcn_mfma_f32_16x16x32_bf16(a, bwR1[ks], acc[1][(ks) & 1], 0, 0, 0); \
      acc[2][(ks) & 1] = __builtin_amdgcn_mfma_f32_16x16x32_bf16(a, bwS[2][ks][lane], acc[2][(ks) & 1], 0, 0, 0); \
      acc[3][(ks) & 1] = __builtin_amdgcn_mfma_f32_16x16x32_bf16(a, bwS[3][ks][lane], acc[3][(ks) & 1], 0, 0, 0); \
    }
    asm volatile("s_waitcnt vmcnt(14)" ::: "memory");   // leftover + burst0-3 done
    __builtin_amdgcn_sched_barrier(0);
    asm volatile("" :: "v"(tvA), "v"(tvB));             // pin poll regs until retired
    MFMA4(0) MFMA4(1) MFMA4(2) MFMA4(3)
    asm volatile("s_waitcnt vmcnt(10)" ::: "memory");   // + burst4-7
    __builtin_amdgcn_sched_barrier(0);
    MFMA4(4) MFMA4(5) MFMA4(6) MFMA4(7)
    asm volatile("s_waitcnt vmcnt(6)" ::: "memory");    // + burst8-11
    __builtin_amdgcn_sched_barrier(0);
    MFMA4(8) MFMA4(9) MFMA4(10) MFMA4(11)
    asm volatile("s_waitcnt vmcnt(2)" ::: "memory");    // + burst12-15 (XI may fly)
    __builtin_amdgcn_sched_barrier(0);
    MFMA4(12) MFMA4(13) MFMA4(14) MFMA4(15)
#undef MFMA4

    // ---- (6) gates with progressive publish (store each h[q] as it's ready)
    unsigned short* pp = hbuf + (((t + 1) & 1) << 12) + (rg * 4) * 512 + j0 + col;
#define GATE_Q(q, OFF)                                                                     \
    {                                                                                      \
      float pf = acc[0][0][q] + acc[0][1][q];                                              \
      float pi = acc[1][0][q] + acc[1][1][q];                                              \
      float po = acc[2][0][q] + acc[2][1][q];                                              \
      float pg = acc[3][0][q] + acc[3][1][q];                                              \
      float fg = sigf(pf), ig = sigf(pi), og = sigf(po), gg = tanh_fast(pg);               \
      float cn = fg * cell[q] + ig * gg;                                                   \
      cell[q] = cn;                                                                        \
      hq[q] = og * tanh_fast(cn);                                                          \
      if (lane < 32) {                                                                     \
        unsigned int hu = f2b(hq[q]);                                                      \
        asm volatile("global_store_short %0, %1, off offset:" #OFF " sc1"                  \
                     :: "v"(pp), "v"(hu) : "memory");                                      \
      }                                                                                    \
    }
    GATE_Q(0, 0) GATE_Q(1, 1024) GATE_Q(2, 2048) GATE_Q(3, 3072)
#undef GATE_Q

    // ---- (7) drain publish (+XI leftover, long landed) -> (8) tag store
    asm volatile("s_waitcnt vmcnt(0)" ::: "memory");
    if (lane == 0) {
      unsigned int tn1 = (unsigned int)(t + 1);
      asm volatile("global_store_dword %0, %1, off sc1" :: "v"(myTag), "v"(tn1) : "memory");
    }

    // ---- (9) POST-tag: out stores (acks complete during next straggler wait)
    if (lane < 32) {
#pragma unroll
      for (int q = 0; q < 4; ++q)
        out[((size_t)t * BATCH + (rg * 4 + q)) * NH + j0 + col] = hq[q];
    }
    xiC0 = xiN0;
    xiC1 = xiN1;
  }

  // ---- final state tail: [h_T ; c_T]
  if (lane < 32) {
    const size_t tail = (size_t)T_STEPS * BATCH * NH;
#pragma unroll
    for (int q = 0; q < 4; ++q) {
      out[tail + (size_t)(rg * 4 + q) * NH + j0 + col] = hq[q];
      out[tail + (size_t)BATCH * NH + (size_t)(rg * 4 + q) * NH + j0 + col] = cell[q];
    }
  }
}

extern "C" void kernel_launch(void* const* d_in, const int* in_sizes, int n_in,
                              void* d_out, int out_size, void* d_ws, size_t ws_size,
                              hipStream_t stream) {
  const float* x  = (const float*)d_in[0];
  const float* h0 = (const float*)d_in[1];
  const float* Wi = (const float*)d_in[2];
  const float* bi = (const float*)d_in[3];
  const float* Wh = (const float*)d_in[4];
  const float* bh = (const float*)d_in[5];
  float* out = (float*)d_out;

  unsigned int* tags = (unsigned int*)d_ws;
  unsigned short* hbuf = (unsigned short*)((char*)d_ws + 256);
  unsigned short* xi = (unsigned short*)((char*)d_ws + 65536);

  init_ws<<<1, 512, 0, stream>>>(h0, tags, hbuf);
  dim3 g1((T_STEPS * BATCH) / BM, G4 / BN);
  xi_gemm<<<g1, 256, 0, stream>>>(x, Wi, bi, bh, xi);
  lstm_rec<<<NWV, 64, 0, stream>>>(Wh, h0, xi, out, tags, hbuf);
}

// Round 15
// 14134.554 us; speedup vs baseline: 1.0166x; 1.0166x over previous
//
#include <hip/hip_runtime.h>
#include <hip/hip_bf16.h>

#define T_STEPS 4096
#define BATCH 8
#define DIN 512
#define NH 512
#define G4 2048
#define NWV 32
#define JPW 16

typedef __attribute__((ext_vector_type(8))) short bf16x8;
typedef __attribute__((ext_vector_type(4))) float f32x4;
typedef __attribute__((ext_vector_type(4))) int i32x4;

__device__ __forceinline__ unsigned short f2b(float f) {
  __hip_bfloat16 h = __float2bfloat16(f);
  return __builtin_bit_cast(unsigned short, h);
}
__device__ __forceinline__ float b2f(unsigned short u) {
  unsigned int x = ((unsigned int)u) << 16;
  return __builtin_bit_cast(float, x);
}
__device__ __forceinline__ float sigf(float x) { return 1.f / (1.f + __expf(-x)); }
__device__ __forceinline__ float tanh_fast(float x) { return 1.f - 2.f / (1.f + __expf(2.f * x)); }

// ---------------- init: tags=0; hbuf parity0 = bf16(h0), parity1 = 0
__global__ __launch_bounds__(512) void init_ws(const float* __restrict__ h0,
                                               unsigned int* __restrict__ tags,
                                               unsigned short* __restrict__ hbuf) {
  int tid = threadIdx.x;
  if (tid < NWV) tags[tid] = 0u;
  for (int i = tid; i < 4096; i += 512) {   // [8 b][512 j] per parity
    int b = i >> 9, j = i & 511;
    hbuf[i] = f2b(h0[b * NH + j]);
    hbuf[4096 + i] = 0;
  }
}

// ---------------- XI = x @ Wi + (bi + bh), swizzled to [t][wv][lane(32)][g*4+q] u16
#define BM 64
#define BN 64
#define BK 16
__global__ __launch_bounds__(256) void xi_gemm(const float* __restrict__ x,
                                               const float* __restrict__ Wi,
                                               const float* __restrict__ bi,
                                               const float* __restrict__ bh,
                                               unsigned short* __restrict__ xi) {
  __shared__ float As[BK][BM + 4];
  __shared__ float Bs[BK][BN + 4];
  const int tid = threadIdx.x;
  const int m0 = blockIdx.x * BM;
  const int n0 = blockIdx.y * BN;
  const int tx = tid & 15, ty = tid >> 4;
  const int arow = tid & 63, ak = (tid >> 6) << 2;
  const int bk = tid >> 4, bn = (tid & 15) << 2;
  float acc[4][4] = {};
  for (int k0 = 0; k0 < DIN; k0 += BK) {
    float4 av = *(const float4*)(x + (size_t)(m0 + arow) * DIN + k0 + ak);
    float4 bv = *(const float4*)(Wi + (size_t)(k0 + bk) * G4 + n0 + bn);
    __syncthreads();
    As[ak + 0][arow] = av.x;
    As[ak + 1][arow] = av.y;
    As[ak + 2][arow] = av.z;
    As[ak + 3][arow] = av.w;
    *(float4*)&Bs[bk][bn] = bv;
    __syncthreads();
#pragma unroll
    for (int kk = 0; kk < BK; ++kk) {
      float am[4], bw[4];
      *(float4*)am = *(const float4*)&As[kk][ty << 2];
      *(float4*)bw = *(const float4*)&Bs[kk][tx << 2];
#pragma unroll
      for (int i = 0; i < 4; ++i)
#pragma unroll
        for (int j = 0; j < 4; ++j) acc[i][j] = fmaf(am[i], bw[j], acc[i][j]);
    }
  }
  const int m_base = m0 + (ty << 2);
  const int n_base = n0 + (tx << 2);
  const int tt = m_base >> 3;
  const int rg = (m_base & 7) >> 2;
  const int gate = n_base >> 9;
  const int wv = (n_base & 511) >> 4;
  const int col0 = n_base & 15;
#pragma unroll
  for (int j = 0; j < 4; ++j) {
    int n = n_base + j;
    float bs = bi[n] + bh[n];
    unsigned long long pk = 0;
#pragma unroll
    for (int i = 0; i < 4; ++i)
      pk |= (unsigned long long)f2b(acc[i][j] + bs) << (16 * i);
    int lane = rg * 16 + col0 + j;
    size_t u16idx = (((size_t)tt * NWV + wv) * 32 + lane) * 16 + gate * 4;
    *(unsigned long long*)(xi + u16idx) = pk;
  }
}

// ---------------- persistent recurrence: 32 blocks x 64 threads (1 wave each).
// R10 protocol exactly (sc1 tag poll -> sc1 data burst -> compute -> sc1 publish
// -> vmcnt(0) -> sc1 tag store -> post-tag out/XI). Two latency micro-opts:
//   (1) pipelined 2-deep tag poll (check cadence RT/2)
//   (2) staged burst waits vmcnt(12/8/4/0), MFMA overlapped with burst tail
__global__ __launch_bounds__(64, 1) void lstm_rec(const float* __restrict__ Wh,
                                                  const float* __restrict__ h0c0,
                                                  const unsigned short* __restrict__ xi,
                                                  float* __restrict__ out,
                                                  unsigned int* tags,
                                                  unsigned short* hbuf) {
  const int wv = blockIdx.x;
  const int j0 = wv * JPW;
  const int lane = threadIdx.x;
  const int col = lane & 15;      // C col / loader batch-row
  const int rg = lane >> 4;       // C row-group / A k-subblock

  __shared__ bf16x8 bwS[4][16][64];   // 64 KiB frag-layout Wh slice

  // ---- prologue: Wh slice -> LDS in frag layout
  {
    const int gp = lane >> 4, cp = lane & 15;
    const float* wsrc = Wh + (size_t)gp * NH + j0 + cp;
#pragma unroll 4
    for (int k = 0; k < 512; ++k) {
      float wval = wsrc[(size_t)k * G4];
      const int ks = k >> 5, kq = (k >> 3) & 3, e = k & 7;
      ((unsigned short*)&bwS[gp][ks][kq * 16 + cp])[e] = f2b(wval);
    }
  }
  __syncthreads();

  bf16x8 bwR0[16], bwR1[16];
#pragma unroll
  for (int ks = 0; ks < 16; ++ks) {
    bwR0[ks] = bwS[0][ks][lane];
    bwR1[ks] = bwS[1][ks][lane];
  }

  f32x4 cell = {0.f, 0.f, 0.f, 0.f};
  if (lane < 32) {
#pragma unroll
    for (int q = 0; q < 4; ++q)
      cell[q] = h0c0[(size_t)(BATCH + rg * 4 + q) * NH + j0 + col];
  }

  // ---- XI(0) preload
  i32x4 xiC0, xiC1, xiN0, xiN1;
  {
    const unsigned short* xp = xi + ((size_t)wv * 32 + (lane & 31)) * 16;
    asm volatile("global_load_dwordx4 %0, %1, off" : "=&v"(xiC0) : "v"(xp));
    asm volatile("global_load_dwordx4 %0, %1, off offset:16" : "=&v"(xiC1) : "v"(xp));
  }
  f32x4 hq = {0.f, 0.f, 0.f, 0.f};

  const unsigned int* tp = tags + (lane & 31);
  unsigned int* myTag = tags + wv;

  for (int t = 0; t < T_STEPS; ++t) {
    // ---- (1) pipelined tag poll: 2 loads in flight, alternate vmcnt(1) checks.
    //      (First iterations also drain prior post-tag out/XI traffic.)
    {
      unsigned int tvA, tvB;
      asm volatile("global_load_dword %0, %1, off sc1" : "=&v"(tvA) : "v"(tp) : "memory");
      for (;;) {
        asm volatile("global_load_dword %0, %1, off sc1" : "=&v"(tvB) : "v"(tp) : "memory");
        asm volatile("s_waitcnt vmcnt(1)" ::: "memory");   // tvA ready
        __builtin_amdgcn_sched_barrier(0);
        if (__all((int)tvA >= t)) break;
        asm volatile("global_load_dword %0, %1, off sc1" : "=&v"(tvA) : "v"(tp) : "memory");
        asm volatile("s_waitcnt vmcnt(1)" ::: "memory");   // tvB ready
        __builtin_amdgcn_sched_barrier(0);
        if (__all((int)tvB >= t)) break;
      }
      asm volatile("s_waitcnt vmcnt(0)" ::: "memory");     // retire leftover poll load
      __builtin_amdgcn_sched_barrier(0);
    }

    // ---- (2) acc seed from XI (VALU only; runs while nothing outstanding)
    f32x4 acc[4][2];
    {
      unsigned int wrd[8] = {(unsigned int)xiC0[0], (unsigned int)xiC0[1],
                             (unsigned int)xiC0[2], (unsigned int)xiC0[3],
                             (unsigned int)xiC1[0], (unsigned int)xiC1[1],
                             (unsigned int)xiC1[2], (unsigned int)xiC1[3]};
      f32x4 z = {0.f, 0.f, 0.f, 0.f};
#pragma unroll
      for (int g = 0; g < 4; ++g) {
#pragma unroll
        for (int q = 0; q < 4; ++q) {
          const int idx = g * 4 + q;
          acc[g][0][q] = b2f((unsigned short)(wrd[idx >> 1] >> ((idx & 1) * 16)));
        }
        acc[g][1] = z;
      }
    }

    // ---- (3) h(t) burst: 16 sc1 dwordx4 issued back-to-back (vmcnt clean here)
    const unsigned short* mb = hbuf + ((t & 1) << 12);
    const unsigned short* ap = mb + (col & 7) * 512 + (rg << 3);
    i32x4 afr[16];
    asm volatile("global_load_dwordx4 %0, %1, off sc1" : "=v"(afr[0]) : "v"(ap));
    asm volatile("global_load_dwordx4 %0, %1, off offset:64 sc1" : "=v"(afr[1]) : "v"(ap));
    asm volatile("global_load_dwordx4 %0, %1, off offset:128 sc1" : "=v"(afr[2]) : "v"(ap));
    asm volatile("global_load_dwordx4 %0, %1, off offset:192 sc1" : "=v"(afr[3]) : "v"(ap));
    asm volatile("global_load_dwordx4 %0, %1, off offset:256 sc1" : "=v"(afr[4]) : "v"(ap));
    asm volatile("global_load_dwordx4 %0, %1, off offset:320 sc1" : "=v"(afr[5]) : "v"(ap));
    asm volatile("global_load_dwordx4 %0, %1, off offset:384 sc1" : "=v"(afr[6]) : "v"(ap));
    asm volatile("global_load_dwordx4 %0, %1, off offset:448 sc1" : "=v"(afr[7]) : "v"(ap));
    asm volatile("global_load_dwordx4 %0, %1, off offset:512 sc1" : "=v"(afr[8]) : "v"(ap));
    asm volatile("global_load_dwordx4 %0, %1, off offset:576 sc1" : "=v"(afr[9]) : "v"(ap));
    asm volatile("global_load_dwordx4 %0, %1, off offset:640 sc1" : "=v"(afr[10]) : "v"(ap));
    asm volatile("global_load_dwordx4 %0, %1, off offset:704 sc1" : "=v"(afr[11]) : "v"(ap));
    asm volatile("global_load_dwordx4 %0, %1, off offset:768 sc1" : "=v"(afr[12]) : "v"(ap));
    asm volatile("global_load_dwordx4 %0, %1, off offset:832 sc1" : "=v"(afr[13]) : "v"(ap));
    asm volatile("global_load_dwordx4 %0, %1, off offset:896 sc1" : "=v"(afr[14]) : "v"(ap));
    asm volatile("global_load_dwordx4 %0, %1, off offset:960 sc1" : "=v"(afr[15]) : "v"(ap));

    // ---- (4) staged consume: vmcnt retires in issue order -> 4 groups of 4 loads,
    //      16 MFMAs each, overlapping compute with the burst tail (rule #18 fences)
#define MFMA4(ks)                                                                          \
    {                                                                                      \
      bf16x8 a = __builtin_bit_cast(bf16x8, afr[ks]);                                      \
      acc[0][(ks) & 1] = __builtin_amdgcn_mfma_f32_16x16x32_bf16(a, bwR0[ks], acc[0][(ks) & 1], 0, 0, 0); \
      acc[1][(ks) & 1] = __builtin_amdgcn_mfma_f32_16x16x32_bf16(a, bwR1[ks], acc[1][(ks) & 1], 0, 0, 0); \
      acc[2][(ks) & 1] = __builtin_amdgcn_mfma_f32_16x16x32_bf16(a, bwS[2][ks][lane], acc[2][(ks) & 1], 0, 0, 0); \
      acc[3][(ks) & 1] = __builtin_amdgcn_mfma_f32_16x16x32_bf16(a, bwS[3][ks][lane], acc[3][(ks) & 1], 0, 0, 0); \
    }
    asm volatile("s_waitcnt vmcnt(12)" ::: "memory");
    __builtin_amdgcn_sched_barrier(0);
    MFMA4(0) MFMA4(1) MFMA4(2) MFMA4(3)
    asm volatile("s_waitcnt vmcnt(8)" ::: "memory");
    __builtin_amdgcn_sched_barrier(0);
    MFMA4(4) MFMA4(5) MFMA4(6) MFMA4(7)
    asm volatile("s_waitcnt vmcnt(4)" ::: "memory");
    __builtin_amdgcn_sched_barrier(0);
    MFMA4(8) MFMA4(9) MFMA4(10) MFMA4(11)
    asm volatile("s_waitcnt vmcnt(0)" ::: "memory");
    __builtin_amdgcn_sched_barrier(0);
    MFMA4(12) MFMA4(13) MFMA4(14) MFMA4(15)
#undef MFMA4

    // ---- (5) gates
#pragma unroll
    for (int q = 0; q < 4; ++q) {
      float pf = acc[0][0][q] + acc[0][1][q];
      float pi = acc[1][0][q] + acc[1][1][q];
      float po = acc[2][0][q] + acc[2][1][q];
      float pg = acc[3][0][q] + acc[3][1][q];
      float fg = sigf(pf), ig = sigf(pi), og = sigf(po), gg = tanh_fast(pg);
      float cn = fg * cell[q] + ig * gg;
      cell[q] = cn;
      hq[q] = og * tanh_fast(cn);
    }

    // ---- (6) publish h(t+1): 4 sc1 u16 stores per lane (own values, R10-proven)
    if (lane < 32) {
      unsigned short* pp = hbuf + (((t + 1) & 1) << 12) + (rg * 4) * 512 + j0 + col;
      unsigned int h0u = f2b(hq[0]), h1u = f2b(hq[1]), h2u = f2b(hq[2]), h3u = f2b(hq[3]);
      asm volatile("global_store_short %0, %1, off sc1" :: "v"(pp), "v"(h0u) : "memory");
      asm volatile("global_store_short %0, %1, off offset:1024 sc1" :: "v"(pp), "v"(h1u) : "memory");
      asm volatile("global_store_short %0, %1, off offset:2048 sc1" :: "v"(pp), "v"(h2u) : "memory");
      asm volatile("global_store_short %0, %1, off offset:3072 sc1" :: "v"(pp), "v"(h3u) : "memory");
    }
    // ---- (7) drain publish (nothing else outstanding)
    asm volatile("s_waitcnt vmcnt(0)" ::: "memory");
    // ---- (8) tag store
    if (lane == 0) {
      unsigned int tn1 = (unsigned int)(t + 1);
      asm volatile("global_store_dword %0, %1, off sc1" :: "v"(myTag), "v"(tn1) : "memory");
    }

    // ---- (9) POST-tag: out stores + XI(t+1) prefetch (acks overlap next poll)
    if (lane < 32) {
#pragma unroll
      for (int q = 0; q < 4; ++q)
        out[((size_t)t * BATCH + (rg * 4 + q)) * NH + j0 + col] = hq[q];
    }
    {
      const int tn = (t + 1 < T_STEPS) ? (t + 1) : t;
      const unsigned short* xp = xi + (((size_t)tn * NWV + wv) * 32 + (lane & 31)) * 16;
      asm volatile("global_load_dwordx4 %0, %1, off" : "=&v"(xiN0) : "v"(xp));
      asm volatile("global_load_dwordx4 %0, %1, off offset:16" : "=&v"(xiN1) : "v"(xp));
    }
    xiC0 = xiN0;
    xiC1 = xiN1;
  }

  // ---- final state tail: [h_T ; c_T]
  if (lane < 32) {
    const size_t tail = (size_t)T_STEPS * BATCH * NH;
#pragma unroll
    for (int q = 0; q < 4; ++q) {
      out[tail + (size_t)(rg * 4 + q) * NH + j0 + col] = hq[q];
      out[tail + (size_t)BATCH * NH + (size_t)(rg * 4 + q) * NH + j0 + col] = cell[q];
    }
  }
}

extern "C" void kernel_launch(void* const* d_in, const int* in_sizes, int n_in,
                              void* d_out, int out_size, void* d_ws, size_t ws_size,
                              hipStream_t stream) {
  const float* x  = (const float*)d_in[0];
  const float* h0 = (const float*)d_in[1];
  const float* Wi = (const float*)d_in[2];
  const float* bi = (const float*)d_in[3];
  const float* Wh = (const float*)d_in[4];
  const float* bh = (const float*)d_in[5];
  float* out = (float*)d_out;

  unsigned int* tags = (unsigned int*)d_ws;
  unsigned short* hbuf = (unsigned short*)((char*)d_ws + 256);
  unsigned short* xi = (unsigned short*)((char*)d_ws + 65536);

  init_ws<<<1, 512, 0, stream>>>(h0, tags, hbuf);
  dim3 g1((T_STEPS * BATCH) / BM, G4 / BN);
  xi_gemm<<<g1, 256, 0, stream>>>(x, Wi, bi, bh, xi);
  lstm_rec<<<NWV, 64, 0, stream>>>(Wh, h0, xi, out, tags, hbuf);
}